// Round 1
// baseline (5677.339 us; speedup 1.0000x reference)
//
#include <hip/hip_runtime.h>
#include <stdint.h>

#define B_ 4096
#define D_ 512
#define H_ 2048

typedef unsigned short ushort_t;
typedef __attribute__((ext_vector_type(8))) short bf16x8;
typedef __attribute__((ext_vector_type(4))) float f32x4;

__device__ __forceinline__ ushort_t f2bf(float f) {
  union { float f; uint32_t u; } v; v.f = f;
  uint32_t u = v.u;
  return (ushort_t)((u + 0x7fffu + ((u >> 16) & 1u)) >> 16);  // RNE, finite inputs
}

__device__ __forceinline__ ushort4 pack4(float a, float b, float c, float d) {
  ushort4 r; r.x = f2bf(a); r.y = f2bf(b); r.z = f2bf(c); r.w = f2bf(d); return r;
}

// ---------------------------------------------------------------------------
// GEMM: C[M][N] = epilogue(A[M][K] * Bt[N][K]^T + bias)
// A, Bt bf16 row-major. TANH_BF16: C = bf16(tanh(.)), else fp32 atomicAdd
// (split-K over blockIdx.z; bias added only by z==0; target pre-zeroed).
// Block 256 thr = 4 waves, tile 128x128, BK=32, wave-tile 64x64 (4x4 MFMAs).
// ---------------------------------------------------------------------------
template<bool TANH_BF16>
__global__ __launch_bounds__(256)
void gemm_bt(const ushort_t* __restrict__ A, const ushort_t* __restrict__ Bt,
             const float* __restrict__ bias, void* __restrict__ Cv,
             int N, int K, int klen)
{
  __shared__ __align__(16) ushort_t As[128 * 32];
  __shared__ __align__(16) ushort_t Bs[128 * 32];
  const int t  = threadIdx.x;
  const int bm = blockIdx.x, bn = blockIdx.y, bz = blockIdx.z;
  const int l  = t & 63, w = t >> 6;
  const int wm = (w & 1) * 64, wn = (w >> 1) * 64;
  const int lm = l & 15, kg = l >> 4;

  f32x4 acc[4][4];
#pragma unroll
  for (int i = 0; i < 4; ++i)
#pragma unroll
    for (int j = 0; j < 4; ++j) acc[i][j] = (f32x4)(0.f);

  const int ra = t >> 2;            // 0..63, staging row
  const int k8 = (t & 3) * 8;       // 0/8/16/24 within BK
  const ushort_t* Ab = A  + (size_t)(bm * 128) * K;
  const ushort_t* Bb = Bt + (size_t)(bn * 128) * K;
  const int k0 = bz * klen;

  for (int kk = k0; kk < k0 + klen; kk += 32) {
    uint4 a0 = *(const uint4*)(Ab + (size_t)ra * K + kk + k8);
    uint4 a1 = *(const uint4*)(Ab + (size_t)(ra + 64) * K + kk + k8);
    uint4 b0 = *(const uint4*)(Bb + (size_t)ra * K + kk + k8);
    uint4 b1 = *(const uint4*)(Bb + (size_t)(ra + 64) * K + kk + k8);
    __syncthreads();
    *(uint4*)(As + ra * 32 + k8)        = a0;
    *(uint4*)(As + (ra + 64) * 32 + k8) = a1;
    *(uint4*)(Bs + ra * 32 + k8)        = b0;
    *(uint4*)(Bs + (ra + 64) * 32 + k8) = b1;
    __syncthreads();

    bf16x8 af[4], bv[4];
#pragma unroll
    for (int i = 0; i < 4; ++i)
      af[i] = *(const bf16x8*)(As + (wm + i * 16 + lm) * 32 + kg * 8);
#pragma unroll
    for (int j = 0; j < 4; ++j)
      bv[j] = *(const bf16x8*)(Bs + (wn + j * 16 + lm) * 32 + kg * 8);
#pragma unroll
    for (int i = 0; i < 4; ++i)
#pragma unroll
      for (int j = 0; j < 4; ++j)
        acc[i][j] = __builtin_amdgcn_mfma_f32_16x16x32_bf16(af[i], bv[j], acc[i][j], 0, 0, 0);
  }

  const int r0 = (l >> 4) * 4;      // C/D: col = lane&15, row = (lane>>4)*4 + reg
#pragma unroll
  for (int i = 0; i < 4; ++i) {
#pragma unroll
    for (int j = 0; j < 4; ++j) {
      const int gcol = bn * 128 + wn + j * 16 + lm;
      const float bvv = bias[gcol];
#pragma unroll
      for (int r = 0; r < 4; ++r) {
        const int grow = bm * 128 + wm + i * 16 + r0 + r;
        float v = acc[i][j][r];
        if (TANH_BF16) {
          ((ushort_t*)Cv)[(size_t)grow * N + gcol] = f2bf(tanhf(v + bvv));
        } else {
          if (bz == 0) v += bvv;
          atomicAdd((float*)Cv + (size_t)grow * N + gcol, v);
        }
      }
    }
  }
}

// ---------------------------------------------------------------------------
// Weight transpose + bf16 cast: W[R][C] fp32 -> Wt[C][R] bf16 (coalesced write)
// ---------------------------------------------------------------------------
template<int R, int C>
__global__ void k_transpose(const float* __restrict__ W, ushort_t* __restrict__ Wt) {
  const int tid = blockIdx.x * 256 + threadIdx.x;   // tid = c*R + r
  if (tid >= R * C) return;
  const int r = tid % R;
  const int c = tid / R;
  Wt[tid] = f2bf(W[(size_t)r * C + c]);
}

// ---------------------------------------------------------------------------
// Elementwise integrator kernels (float4-vectorized over B_*D_/4 elements).
// Each kernel that precedes a GEMM2 also zeroes that GEMM2's split-K target.
// ---------------------------------------------------------------------------
#define EW_IDX int i = blockIdx.x * 256 + threadIdx.x; if (i >= n4) return;
#define ZERO4 make_float4(0.f, 0.f, 0.f, 0.f)

__global__ void k_cvt(const float4* __restrict__ src, ushort4* __restrict__ abf,
                      float4* __restrict__ zt, int n4) {
  EW_IDX
  float4 v = src[i];
  abf[i] = pack4(v.x, v.y, v.z, v.w);
  zt[i] = ZERO4;
}

// RK4 stage 1: Abf = bf16(y + a*k1), ksum = k1, zero F
__global__ void k_e1(const float4* __restrict__ y, const float4* __restrict__ k, float a,
                     ushort4* __restrict__ abf, float4* __restrict__ ksum,
                     float4* __restrict__ zt, int n4) {
  EW_IDX
  float4 yv = y[i], kv = k[i];
  abf[i] = pack4(yv.x + a * kv.x, yv.y + a * kv.y, yv.z + a * kv.z, yv.w + a * kv.w);
  ksum[i] = kv;
  zt[i] = ZERO4;
}

// RK4 stages 2/3: ksum += 2*F; Abf = bf16(y + a*F); F = 0 (read-then-zero)
__global__ void k_e23(const float4* __restrict__ y, float4* __restrict__ F, float a,
                      ushort4* __restrict__ abf, float4* __restrict__ ksum, int n4) {
  EW_IDX
  float4 yv = y[i], fv = F[i], s = ksum[i];
  abf[i] = pack4(yv.x + a * fv.x, yv.y + a * fv.y, yv.z + a * fv.z, yv.w + a * fv.w);
  ksum[i] = make_float4(s.x + 2.f * fv.x, s.y + 2.f * fv.y, s.z + 2.f * fv.z, s.w + 2.f * fv.w);
  F[i] = ZERO4;
}

// RK4 final: ynew = y + dt/6*(ksum + k4); Abf = bf16(ynew); zero next f-target
__global__ void k_e4(const float4* __restrict__ yin, const float4* __restrict__ ks,
                     const float4* __restrict__ F, float dt6, float4* __restrict__ yout,
                     ushort4* __restrict__ abf, float4* __restrict__ zt, int n4) {
  EW_IDX
  float4 yv = yin[i], s = ks[i], fv = F[i];
  float4 yn = make_float4(yv.x + dt6 * (s.x + fv.x), yv.y + dt6 * (s.y + fv.y),
                          yv.z + dt6 * (s.z + fv.z), yv.w + dt6 * (s.w + fv.w));
  yout[i] = yn;
  abf[i] = pack4(yn.x, yn.y, yn.z, yn.w);
  zt[i] = ZERO4;
}

// ABM predictor: S = y + c(19h0-5h1+h2); Abf = bf16(y + c(55h0-59h1+37h2-9h3)); zero F
__global__ void k_pred(const float4* __restrict__ y, const float4* __restrict__ h0,
                       const float4* __restrict__ h1, const float4* __restrict__ h2,
                       const float4* __restrict__ h3, float c,
                       float4* __restrict__ S, ushort4* __restrict__ abf,
                       float4* __restrict__ zt, int n4) {
  EW_IDX
  float4 yv = y[i], a0 = h0[i], a1 = h1[i], a2 = h2[i], a3 = h3[i];
  S[i] = make_float4(yv.x + c * (19.f * a0.x - 5.f * a1.x + a2.x),
                     yv.y + c * (19.f * a0.y - 5.f * a1.y + a2.y),
                     yv.z + c * (19.f * a0.z - 5.f * a1.z + a2.z),
                     yv.w + c * (19.f * a0.w - 5.f * a1.w + a2.w));
  abf[i] = pack4(yv.x + c * (55.f * a0.x - 59.f * a1.x + 37.f * a2.x - 9.f * a3.x),
                 yv.y + c * (55.f * a0.y - 59.f * a1.y + 37.f * a2.y - 9.f * a3.y),
                 yv.z + c * (55.f * a0.z - 59.f * a1.z + 37.f * a2.z - 9.f * a3.z),
                 yv.w + c * (55.f * a0.w - 59.f * a1.w + 37.f * a2.w - 9.f * a3.w));
  zt[i] = ZERO4;
}

// corrector sweep: Abf = bf16(S + 9c*F); F = 0
__global__ void k_corr(const float4* __restrict__ S, float4* __restrict__ F, float c9,
                       ushort4* __restrict__ abf, int n4) {
  EW_IDX
  float4 sv = S[i], fv = F[i];
  abf[i] = pack4(sv.x + c9 * fv.x, sv.y + c9 * fv.y, sv.z + c9 * fv.z, sv.w + c9 * fv.w);
  F[i] = ZERO4;
}

// final corrector: ynew = S + 9c*F -> yout; optionally Abf and zero f-target
__global__ void k_corrfin(const float4* __restrict__ S, const float4* __restrict__ F, float c9,
                          float4* __restrict__ yout, ushort4* __restrict__ abf,
                          float4* __restrict__ zt, int n4) {
  EW_IDX
  float4 sv = S[i], fv = F[i];
  float4 p = make_float4(sv.x + c9 * fv.x, sv.y + c9 * fv.y, sv.z + c9 * fv.z, sv.w + c9 * fv.w);
  yout[i] = p;
  if (abf) abf[i] = pack4(p.x, p.y, p.z, p.w);
  if (zt) zt[i] = ZERO4;
}

// ---------------------------------------------------------------------------
extern "C" void kernel_launch(void* const* d_in, const int* in_sizes, int n_in,
                              void* d_out, int out_size, void* d_ws, size_t ws_size,
                              hipStream_t stream) {
  const float* x  = (const float*)d_in[0];
  const float* W1 = (const float*)d_in[1];
  const float* b1 = (const float*)d_in[2];
  const float* W2 = (const float*)d_in[3];
  const float* b2 = (const float*)d_in[4];
  float* out = (float*)d_out;

  uint8_t* ws = (uint8_t*)d_ws;
  const size_t MB = 1024 * 1024;
  ushort_t* W1t = (ushort_t*)(ws);            // [H][D] bf16, 2 MB
  ushort_t* W2t = (ushort_t*)(ws + 2 * MB);   // [D][H] bf16, 2 MB
  ushort_t* Abf = (ushort_t*)(ws + 4 * MB);   // GEMM1 input, bf16 [B][D], 4 MB
  ushort_t* T   = (ushort_t*)(ws + 8 * MB);   // activations bf16 [B][H], 16 MB
  float* ybuf   = (float*)(ws + 24 * MB);     // state y
  float* Sbuf   = (float*)(ws + 32 * MB);     // ksum (RK4) / S (ABM)
  float* Fbuf   = (float*)(ws + 40 * MB);     // transient f outputs
  float* hb[4]  = { (float*)(ws + 48 * MB), (float*)(ws + 56 * MB),
                    (float*)(ws + 64 * MB), (float*)(ws + 72 * MB) };  // f-history

  const int n4 = (B_ * D_) / 4;
  const dim3 EB(256), EG(n4 / 256);
  const float dt = 1.0f / 20.0f;
  const float c = dt / 24.0f, c9 = 9.0f * c, dt6 = dt / 6.0f;

  k_transpose<D_, H_><<<(D_ * H_) / 256, 256, 0, stream>>>(W1, W1t);
  k_transpose<H_, D_><<<(D_ * H_) / 256, 256, 0, stream>>>(W2, W2t);

  auto G1 = [&]() {  // T = bf16(tanh(Abf*W1 + b1)), grid 32x16
    gemm_bt<true><<<dim3(B_ / 128, H_ / 128, 1), 256, 0, stream>>>(Abf, W1t, b1, (void*)T, H_, D_, D_);
  };
  auto G2 = [&](float* dst) {  // dst += T*W2 + b2 (split-K=4, atomic), grid 32x4x4
    gemm_bt<false><<<dim3(B_ / 128, D_ / 128, 4), 256, 0, stream>>>(T, W2t, b2, (void*)dst, D_, H_, H_ / 4);
  };

  // ---- eval #0: f(x) -> hb[0] ----
  k_cvt<<<EG, EB, 0, stream>>>((const float4*)x, (ushort4*)Abf, (float4*)hb[0], n4);
  G1(); G2(hb[0]);

  // ---- RK4 bootstrap: 3 steps (k1 reused from history; f(y_new) -> hb[s+1]) ----
  for (int s = 0; s < 3; ++s) {
    const float4* yin = (const float4*)(s == 0 ? x : (const float*)ybuf);
    k_e1<<<EG, EB, 0, stream>>>(yin, (const float4*)hb[s], 0.5f * dt,
                                (ushort4*)Abf, (float4*)Sbuf, (float4*)Fbuf, n4);
    G1(); G2(Fbuf);                                         // k2
    k_e23<<<EG, EB, 0, stream>>>(yin, (float4*)Fbuf, 0.5f * dt, (ushort4*)Abf, (float4*)Sbuf, n4);
    G1(); G2(Fbuf);                                         // k3
    k_e23<<<EG, EB, 0, stream>>>(yin, (float4*)Fbuf, dt, (ushort4*)Abf, (float4*)Sbuf, n4);
    G1(); G2(Fbuf);                                         // k4
    k_e4<<<EG, EB, 0, stream>>>(yin, (const float4*)Sbuf, (const float4*)Fbuf, dt6,
                                (float4*)ybuf, (ushort4*)Abf, (float4*)hb[s + 1], n4);
    G1(); G2(hb[s + 1]);                                    // f(y_new)
  }

  // ---- ABM-4 predictor-corrector, 17 steps ----
  int i0 = 3, i1 = 2, i2 = 1, i3 = 0;  // h0=f3, h1=f2, h2=f1, h3=f0
  for (int st = 0; st < 17; ++st) {
    const bool last = (st == 16);
    k_pred<<<EG, EB, 0, stream>>>((const float4*)ybuf, (const float4*)hb[i0], (const float4*)hb[i1],
                                  (const float4*)hb[i2], (const float4*)hb[i3], c,
                                  (float4*)Sbuf, (ushort4*)Abf, (float4*)Fbuf, n4);
    G1(); G2(Fbuf);                                         // f(pred0)
    k_corr<<<EG, EB, 0, stream>>>((const float4*)Sbuf, (float4*)Fbuf, c9, (ushort4*)Abf, n4);
    G1(); G2(Fbuf);                                         // f(pred1)
    k_corr<<<EG, EB, 0, stream>>>((const float4*)Sbuf, (float4*)Fbuf, c9, (ushort4*)Abf, n4);
    G1(); G2(Fbuf);                                         // f(pred2)
    if (last) {
      k_corrfin<<<EG, EB, 0, stream>>>((const float4*)Sbuf, (const float4*)Fbuf, c9,
                                       (float4*)out, (ushort4*)nullptr, (float4*)nullptr, n4);
    } else {
      k_corrfin<<<EG, EB, 0, stream>>>((const float4*)Sbuf, (const float4*)Fbuf, c9,
                                       (float4*)ybuf, (ushort4*)Abf, (float4*)hb[i3], n4);
      G1(); G2(hb[i3]);                                     // f_new -> old h3 slot
      const int nh = i3; i3 = i2; i2 = i1; i1 = i0; i0 = nh;
    }
  }

  (void)in_sizes; (void)n_in; (void)out_size; (void)ws_size;
}

// Round 2
// 4447.057 us; speedup vs baseline: 1.2767x; 1.2767x over previous
//
#include <hip/hip_runtime.h>
#include <stdint.h>

#define B_ 4096
#define D_ 512
#define H_ 2048
#define BD4 (B_ * D_ / 4)

typedef unsigned short ushort_t;
typedef __attribute__((ext_vector_type(8))) short bf16x8;
typedef __attribute__((ext_vector_type(4))) float f32x4;

__device__ __forceinline__ ushort_t f2bf(float f) {
  union { float f; uint32_t u; } v; v.f = f;
  uint32_t u = v.u;
  return (ushort_t)((u + 0x7fffu + ((u >> 16) & 1u)) >> 16);  // RNE, finite inputs
}

__device__ __forceinline__ ushort4 pack4(float a, float b, float c, float d) {
  ushort4 r; r.x = f2bf(a); r.y = f2bf(b); r.z = f2bf(c); r.w = f2bf(d); return r;
}

// async global->LDS, 16B per lane; LDS dest = wave-uniform base + lane*16
__device__ __forceinline__ void gl2lds16(const ushort_t* g, ushort_t* l) {
  __builtin_amdgcn_global_load_lds(
      (const __attribute__((address_space(1))) unsigned int*)(const void*)g,
      (__attribute__((address_space(3))) unsigned int*)(void*)l,
      16, 0, 0);
}

// ---------------------------------------------------------------------------
// GEMM: C = A[M][K] * Bt[N][K]^T (+bias).  A,Bt bf16 row-major.
// TANH_BF16: C = bf16(tanh(.+bias)) at [row][N].  Else: fp32 partial store to
// ((float*)Cv + bz*pstride), NO bias (added in the reduce kernel).
// Block 256 = 4 waves, tile 128x128, BK=32, wave-tile 64x64 (4x4 MFMAs).
// Staging via global_load_lds dwordx4: wave w stages 1KB chunks {2w,2w+1} of
// As and Bs; chunk c = LDS bytes [c*1024,c*1024+1024) = rows 16c..16c+15.
// ---------------------------------------------------------------------------
template<bool TANH_BF16>
__global__ __launch_bounds__(256)
void gemm_bt(const ushort_t* __restrict__ A, const ushort_t* __restrict__ Bt,
             const float* __restrict__ bias, void* __restrict__ Cv,
             int N, int K, int klen, size_t pstride)
{
  __shared__ __align__(16) ushort_t As[128 * 32];
  __shared__ __align__(16) ushort_t Bs[128 * 32];
  const int t  = threadIdx.x;
  const int bm = blockIdx.x, bn = blockIdx.y, bz = blockIdx.z;
  const int l  = t & 63, w = t >> 6;
  const int wm = (w & 1) * 64, wn = (w >> 1) * 64;
  const int lm = l & 15, kg = l >> 4;

  f32x4 acc[4][4];
#pragma unroll
  for (int i = 0; i < 4; ++i)
#pragma unroll
    for (int j = 0; j < 4; ++j) acc[i][j] = (f32x4)(0.f);

  // staging addresses: lane i of chunk c -> row 16c + i/4, bf16 col (i%4)*8
  const int c0  = 2 * w, c1 = c0 + 1;
  const int sr0 = c0 * 16 + (l >> 2);
  const int sr1 = c1 * 16 + (l >> 2);
  const int sc  = (l & 3) * 8;
  const ushort_t* Ab = A  + (size_t)(bm * 128) * K;
  const ushort_t* Bb = Bt + (size_t)(bn * 128) * K;
  ushort_t* lA0 = As + c0 * 512;   // wave-uniform LDS bases
  ushort_t* lA1 = As + c1 * 512;
  ushort_t* lB0 = Bs + c0 * 512;
  ushort_t* lB1 = Bs + c1 * 512;
  const int k0 = bz * klen;

  for (int kk = k0; kk < k0 + klen; kk += 32) {
    __syncthreads();   // prev iter's ds_reads done before LDS overwrite
    gl2lds16(Ab + (size_t)sr0 * K + kk + sc, lA0);
    gl2lds16(Ab + (size_t)sr1 * K + kk + sc, lA1);
    gl2lds16(Bb + (size_t)sr0 * K + kk + sc, lB0);
    gl2lds16(Bb + (size_t)sr1 * K + kk + sc, lB1);
    __syncthreads();   // drains vmcnt(0): staged data visible

    bf16x8 af[4], bv[4];
#pragma unroll
    for (int i = 0; i < 4; ++i)
      af[i] = *(const bf16x8*)(As + (wm + i * 16 + lm) * 32 + kg * 8);
#pragma unroll
    for (int j = 0; j < 4; ++j)
      bv[j] = *(const bf16x8*)(Bs + (wn + j * 16 + lm) * 32 + kg * 8);
#pragma unroll
    for (int i = 0; i < 4; ++i)
#pragma unroll
      for (int j = 0; j < 4; ++j)
        acc[i][j] = __builtin_amdgcn_mfma_f32_16x16x32_bf16(af[i], bv[j], acc[i][j], 0, 0, 0);
  }

  const int r0 = (l >> 4) * 4;   // C/D: col = lane&15, row = (lane>>4)*4 + reg
#pragma unroll
  for (int i = 0; i < 4; ++i) {
#pragma unroll
    for (int j = 0; j < 4; ++j) {
      const int gcol = bn * 128 + wn + j * 16 + lm;
#pragma unroll
      for (int r = 0; r < 4; ++r) {
        const int grow = bm * 128 + wm + i * 16 + r0 + r;
        if (TANH_BF16) {
          ((ushort_t*)Cv)[(size_t)grow * N + gcol] = f2bf(tanhf(acc[i][j][r] + bias[gcol]));
        } else {
          ((float*)Cv + (size_t)bz * pstride)[(size_t)grow * N + gcol] = acc[i][j][r];
        }
      }
    }
  }
}

// ---------------------------------------------------------------------------
// Weight transpose + bf16 cast: W[R][C] fp32 -> Wt[C][R] bf16
// ---------------------------------------------------------------------------
template<int R, int C>
__global__ void k_transpose(const float* __restrict__ W, ushort_t* __restrict__ Wt) {
  const int tid = blockIdx.x * 256 + threadIdx.x;   // tid = c*R + r
  if (tid >= R * C) return;
  const int r = tid % R;
  const int c = tid / R;
  Wt[tid] = f2bf(W[(size_t)r * C + c]);
}

// ---------------------------------------------------------------------------
// Fused split-K reduce + integrator elementwise kernels.
// P holds 4 fp32 partials contiguously (P[q*BD4 + i]); fsum = SUM + b2 bias.
// ---------------------------------------------------------------------------
#define EW_IDX int i = blockIdx.x * 256 + threadIdx.x; if (i >= n4) return;

__device__ __forceinline__ float4 redsum(const float4* __restrict__ P,
                                         const float4* __restrict__ b2, int i) {
  float4 a = P[i], b = P[i + BD4], c = P[i + 2 * BD4], d = P[i + 3 * BD4];
  float4 e = b2[i & 127];   // D_=512 -> 128 float4 bias entries per row
  return make_float4(a.x + b.x + c.x + d.x + e.x,
                     a.y + b.y + c.y + d.y + e.y,
                     a.z + b.z + c.z + d.z + e.z,
                     a.w + b.w + c.w + d.w + e.w);
}

__global__ void k_cvt(const float4* __restrict__ src, ushort4* __restrict__ abf, int n4) {
  EW_IDX
  float4 v = src[i];
  abf[i] = pack4(v.x, v.y, v.z, v.w);
}

// RK4 stage 1: k1 = red(P); hb = k1; ksum = k1; Abf = bf16(y + a*k1)
__global__ void r_e1(const float4* __restrict__ P, const float4* __restrict__ b2,
                     float4* __restrict__ hb, const float4* __restrict__ y, float a,
                     ushort4* __restrict__ abf, float4* __restrict__ ksum, int n4) {
  EW_IDX
  float4 k = redsum(P, b2, i), yv = y[i];
  hb[i] = k;
  ksum[i] = k;
  abf[i] = pack4(yv.x + a * k.x, yv.y + a * k.y, yv.z + a * k.z, yv.w + a * k.w);
}

// RK4 stages 2/3: f = red(P); ksum += 2f; Abf = bf16(y + a*f)
__global__ void r_e23(const float4* __restrict__ P, const float4* __restrict__ b2,
                      const float4* __restrict__ y, float a,
                      ushort4* __restrict__ abf, float4* __restrict__ ksum, int n4) {
  EW_IDX
  float4 f = redsum(P, b2, i), yv = y[i], s = ksum[i];
  abf[i] = pack4(yv.x + a * f.x, yv.y + a * f.y, yv.z + a * f.z, yv.w + a * f.w);
  ksum[i] = make_float4(s.x + 2.f * f.x, s.y + 2.f * f.y, s.z + 2.f * f.z, s.w + 2.f * f.w);
}

// RK4 final: k4 = red(P); yn = y + dt6*(ksum + k4); yout = yn; Abf = bf16(yn)
__global__ void r_e4(const float4* __restrict__ P, const float4* __restrict__ b2,
                     const float4* __restrict__ yin, const float4* __restrict__ ks, float dt6,
                     float4* __restrict__ yout, ushort4* __restrict__ abf, int n4) {
  EW_IDX
  float4 k = redsum(P, b2, i), yv = yin[i], s = ks[i];
  float4 yn = make_float4(yv.x + dt6 * (s.x + k.x), yv.y + dt6 * (s.y + k.y),
                          yv.z + dt6 * (s.z + k.z), yv.w + dt6 * (s.w + k.w));
  yout[i] = yn;
  abf[i] = pack4(yn.x, yn.y, yn.z, yn.w);
}

// ABM predictor: h0 = red(P); hnew = h0; S = y + c(19h0-5h1+h2);
// Abf = bf16(y + c(55h0-59h1+37h2-9h3))
__global__ void r_pred(const float4* __restrict__ P, const float4* __restrict__ b2,
                       float4* __restrict__ hnew, const float4* __restrict__ y,
                       const float4* __restrict__ h1, const float4* __restrict__ h2,
                       const float4* __restrict__ h3, float c,
                       float4* __restrict__ S, ushort4* __restrict__ abf, int n4) {
  EW_IDX
  float4 h0 = redsum(P, b2, i);
  hnew[i] = h0;
  float4 yv = y[i], a1 = h1[i], a2 = h2[i], a3 = h3[i];
  S[i] = make_float4(yv.x + c * (19.f * h0.x - 5.f * a1.x + a2.x),
                     yv.y + c * (19.f * h0.y - 5.f * a1.y + a2.y),
                     yv.z + c * (19.f * h0.z - 5.f * a1.z + a2.z),
                     yv.w + c * (19.f * h0.w - 5.f * a1.w + a2.w));
  abf[i] = pack4(yv.x + c * (55.f * h0.x - 59.f * a1.x + 37.f * a2.x - 9.f * a3.x),
                 yv.y + c * (55.f * h0.y - 59.f * a1.y + 37.f * a2.y - 9.f * a3.y),
                 yv.z + c * (55.f * h0.z - 59.f * a1.z + 37.f * a2.z - 9.f * a3.z),
                 yv.w + c * (55.f * h0.w - 59.f * a1.w + 37.f * a2.w - 9.f * a3.w));
}

// corrector sweep: fp = red(P); Abf = bf16(S + 9c*fp)
__global__ void r_corr(const float4* __restrict__ P, const float4* __restrict__ b2,
                       const float4* __restrict__ S, float c9,
                       ushort4* __restrict__ abf, int n4) {
  EW_IDX
  float4 f = redsum(P, b2, i), sv = S[i];
  abf[i] = pack4(sv.x + c9 * f.x, sv.y + c9 * f.y, sv.z + c9 * f.z, sv.w + c9 * f.w);
}

// final corrector: yn = S + 9c*red(P); yout = yn; optionally Abf = bf16(yn)
__global__ void r_corrfin(const float4* __restrict__ P, const float4* __restrict__ b2,
                          const float4* __restrict__ S, float c9,
                          float4* __restrict__ yout, ushort4* __restrict__ abf, int n4) {
  EW_IDX
  float4 f = redsum(P, b2, i), sv = S[i];
  float4 p = make_float4(sv.x + c9 * f.x, sv.y + c9 * f.y, sv.z + c9 * f.z, sv.w + c9 * f.w);
  yout[i] = p;
  if (abf) abf[i] = pack4(p.x, p.y, p.z, p.w);
}

// ---------------------------------------------------------------------------
extern "C" void kernel_launch(void* const* d_in, const int* in_sizes, int n_in,
                              void* d_out, int out_size, void* d_ws, size_t ws_size,
                              hipStream_t stream) {
  const float* x  = (const float*)d_in[0];
  const float* W1 = (const float*)d_in[1];
  const float* b1 = (const float*)d_in[2];
  const float* W2 = (const float*)d_in[3];
  const float* b2 = (const float*)d_in[4];
  float* out = (float*)d_out;

  uint8_t* ws = (uint8_t*)d_ws;
  const size_t MB = 1024 * 1024;
  ushort_t* W1t = (ushort_t*)(ws);            // [H][D] bf16, 2 MB
  ushort_t* W2t = (ushort_t*)(ws + 2 * MB);   // [D][H] bf16, 2 MB
  ushort_t* Abf = (ushort_t*)(ws + 4 * MB);   // GEMM1 input bf16 [B][D], 4 MB
  ushort_t* T   = (ushort_t*)(ws + 8 * MB);   // activations bf16 [B][H], 16 MB
  float* ybuf   = (float*)(ws + 24 * MB);     // state y (8 MB)
  float* Sbuf   = (float*)(ws + 32 * MB);     // ksum (RK4) / S (ABM) (8 MB)
  float* hb[4]  = { (float*)(ws + 40 * MB), (float*)(ws + 48 * MB),
                    (float*)(ws + 56 * MB), (float*)(ws + 64 * MB) };  // f-history
  float* P      = (float*)(ws + 72 * MB);     // 4 split-K partials, 32 MB

  const int n4 = BD4;
  const dim3 EB(256), EG(n4 / 256);
  const float dt = 1.0f / 20.0f;
  const float c = dt / 24.0f, c9 = 9.0f * c, dt6 = dt / 6.0f;
  const size_t BD = (size_t)B_ * D_;

  k_transpose<D_, H_><<<(D_ * H_) / 256, 256, 0, stream>>>(W1, W1t);
  k_transpose<H_, D_><<<(H_ * D_) / 256, 256, 0, stream>>>(W2, W2t);

  auto G1 = [&]() {  // T = bf16(tanh(Abf*W1 + b1)), grid 32x16
    gemm_bt<true><<<dim3(B_ / 128, H_ / 128, 1), 256, 0, stream>>>(
        Abf, W1t, b1, (void*)T, H_, D_, D_, 0);
  };
  auto G2 = [&]() {  // P[bz] = T*W2 (split-K=4, plain stores, no bias)
    gemm_bt<false><<<dim3(B_ / 128, D_ / 128, 4), 256, 0, stream>>>(
        T, W2t, b2, (void*)P, D_, H_, H_ / 4, BD);
  };
  const float4* Pf = (const float4*)P;
  const float4* b2f = (const float4*)b2;

  // ---- eval #0: f(x) -> P ----
  k_cvt<<<EG, EB, 0, stream>>>((const float4*)x, (ushort4*)Abf, n4);
  G1(); G2();

  // ---- RK4 bootstrap: 3 steps; P at loop entry holds partials of f(y_s) ----
  for (int s = 0; s < 3; ++s) {
    const float4* yin = (const float4*)(s == 0 ? x : (const float*)ybuf);
    r_e1<<<EG, EB, 0, stream>>>(Pf, b2f, (float4*)hb[s], yin, 0.5f * dt,
                                (ushort4*)Abf, (float4*)Sbuf, n4);
    G1(); G2();                                        // k2
    r_e23<<<EG, EB, 0, stream>>>(Pf, b2f, yin, 0.5f * dt, (ushort4*)Abf, (float4*)Sbuf, n4);
    G1(); G2();                                        // k3
    r_e23<<<EG, EB, 0, stream>>>(Pf, b2f, yin, dt, (ushort4*)Abf, (float4*)Sbuf, n4);
    G1(); G2();                                        // k4
    r_e4<<<EG, EB, 0, stream>>>(Pf, b2f, yin, (const float4*)Sbuf, dt6,
                                (float4*)ybuf, (ushort4*)Abf, n4);
    G1(); G2();                                        // f(y_{s+1})
  }

  // ---- ABM-4 predictor-corrector, 17 steps ----
  // slot n receives the incoming h0 (= reduce of P); h1,h2,h3 are older.
  int n = 3;
  for (int st = 0; st < 17; ++st) {
    const bool last = (st == 16);
    r_pred<<<EG, EB, 0, stream>>>(Pf, b2f, (float4*)hb[n], (const float4*)ybuf,
                                  (const float4*)hb[(n + 3) & 3], (const float4*)hb[(n + 2) & 3],
                                  (const float4*)hb[(n + 1) & 3], c,
                                  (float4*)Sbuf, (ushort4*)Abf, n4);
    G1(); G2();                                        // f(pred0)
    r_corr<<<EG, EB, 0, stream>>>(Pf, b2f, (const float4*)Sbuf, c9, (ushort4*)Abf, n4);
    G1(); G2();                                        // f(pred1)
    r_corr<<<EG, EB, 0, stream>>>(Pf, b2f, (const float4*)Sbuf, c9, (ushort4*)Abf, n4);
    G1(); G2();                                        // f(pred2)
    if (last) {
      r_corrfin<<<EG, EB, 0, stream>>>(Pf, b2f, (const float4*)Sbuf, c9,
                                       (float4*)out, (ushort4*)nullptr, n4);
    } else {
      r_corrfin<<<EG, EB, 0, stream>>>(Pf, b2f, (const float4*)Sbuf, c9,
                                       (float4*)ybuf, (ushort4*)Abf, n4);
      G1(); G2();                                      // f(y_{n+1}) -> next h0
      n = (n + 1) & 3;
    }
  }

  (void)in_sizes; (void)n_in; (void)out_size; (void)ws_size;
}